// Round 9
// baseline (145.338 us; speedup 1.0000x reference)
//
#include <hip/hip_runtime.h>
#include <hip/hip_bf16.h>
#include <stdint.h>

typedef __bf16 bf16_t;
typedef bf16_t bf16x8 __attribute__((ext_vector_type(8)));
typedef float  f32x4  __attribute__((ext_vector_type(4)));
typedef float  f32x16 __attribute__((ext_vector_type(16)));

#define GLOAD16(gp, lp) __builtin_amdgcn_global_load_lds( \
    (const __attribute__((address_space(1))) void*)(gp),  \
    (__attribute__((address_space(3))) void*)(lp), 16, 0, 0)

#define EXP2F(x) __builtin_amdgcn_exp2f(x)

__device__ inline uint32_t pack2(float lo, float hi) {
    union { bf16_t h[2]; uint32_t u; } x;
    x.h[0] = (bf16_t)lo; x.h[1] = (bf16_t)hi;
    return x.u;
}

// ---------------------------------------------------------------------------
// Weight transpose + fp32->bf16 convert: Wt[n][k] = (bf16) W[k][n], 1024x1024
// ---------------------------------------------------------------------------
__global__ __launch_bounds__(256) void wtrans_kernel(
    const float* __restrict__ Wq, const float* __restrict__ Wk,
    const float* __restrict__ Wv, const float* __restrict__ We,
    bf16_t* __restrict__ WqT, bf16_t* __restrict__ WkT,
    bf16_t* __restrict__ WvT, bf16_t* __restrict__ WeT)
{
    __shared__ bf16_t T[64][65];
    const float* W = (blockIdx.z == 0) ? Wq : (blockIdx.z == 1) ? Wk
                   : (blockIdx.z == 2) ? Wv : We;
    bf16_t* O = (blockIdx.z == 0) ? WqT : (blockIdx.z == 1) ? WkT
              : (blockIdx.z == 2) ? WvT : WeT;
    const int k0 = blockIdx.y * 64, n0 = blockIdx.x * 64;
    const int t = threadIdx.x;
    for (int i = 0; i < 16; ++i) {
        int flat = t + i * 256;
        int r = flat >> 6, c = flat & 63;
        T[r][c] = (bf16_t)W[(size_t)(k0 + r) * 1024 + n0 + c];
    }
    __syncthreads();
    for (int i = 0; i < 16; ++i) {
        int flat = t + i * 256;
        int n = flat >> 6, kk = flat & 63;
        O[(size_t)(n0 + n) * 1024 + k0 + kk] = T[kk][n];
    }
}

// ---------------------------------------------------------------------------
// Streaming fp32 -> bf16 convert for Q, K, V (4096x1024 each).
// ---------------------------------------------------------------------------
__global__ __launch_bounds__(256)
void cvt_kernel(const float* __restrict__ X0, const float* __restrict__ X1,
                const float* __restrict__ X2,
                bf16_t* __restrict__ Y0, bf16_t* __restrict__ Y1,
                bf16_t* __restrict__ Y2)
{
    const float* X = (blockIdx.y == 0) ? X0 : (blockIdx.y == 1) ? X1 : X2;
    bf16_t*      Y = (blockIdx.y == 0) ? Y0 : (blockIdx.y == 1) ? Y1 : Y2;
    size_t i0 = ((size_t)blockIdx.x * 256 + threadIdx.x) * 8;
    float4 v0 = *(const float4*)(X + i0);
    float4 v1 = *(const float4*)(X + i0 + 4);
    bf16x8 pv;
    pv[0] = (bf16_t)v0.x; pv[1] = (bf16_t)v0.y;
    pv[2] = (bf16_t)v0.z; pv[3] = (bf16_t)v0.w;
    pv[4] = (bf16_t)v1.x; pv[5] = (bf16_t)v1.y;
    pv[6] = (bf16_t)v1.z; pv[7] = (bf16_t)v1.w;
    *(bf16x8*)(Y + i0) = pv;
}

// ---------------------------------------------------------------------------
// GEMM v3 (all-bf16, m97-class): C = A @ Bt^T + bias.  M=4096,N=1024,K=1024.
// Both operands via global_load_lds w=16, XOR-swizzle (pre-swz source),
// XCD-locality block remap.  Unchanged from R7 (proven).
// ---------------------------------------------------------------------------
template<bool BATCHED>
__global__ __launch_bounds__(256)
void gemm3_kernel(const bf16_t* __restrict__ A0, const bf16_t* __restrict__ A1,
                  const bf16_t* __restrict__ A2,
                  const bf16_t* __restrict__ B0, const bf16_t* __restrict__ B1,
                  const bf16_t* __restrict__ B2,
                  const float* __restrict__ b0, const float* __restrict__ b1,
                  const float* __restrict__ b2,
                  void* __restrict__ C0, void* __restrict__ C1,
                  void* __restrict__ C2)
{
    constexpr int M = 4096, K = 1024, N = 1024;
    __shared__ bf16_t As[128 * 64];
    __shared__ bf16_t Bs[128 * 64];

    const int msel = BATCHED ? blockIdx.y : 0;
    const bf16_t* Ab   = (msel == 0) ? A0 : (msel == 1) ? A1 : A2;
    const bf16_t* Bt   = (msel == 0) ? B0 : (msel == 1) ? B1 : B2;
    const float*  bias = (msel == 0) ? b0 : (msel == 1) ? b1 : b2;
    void*         Cv   = (msel == 0) ? C0 : (msel == 1) ? C1 : C2;
    const int omode = BATCHED ? ((msel == 2) ? 2 : 0) : 1;

    const int xcd = blockIdx.x & 7, idx = blockIdx.x >> 3;
    const int bm = (xcd << 2) | (idx >> 3), bn = idx & 7;
    const int row0 = bm * 128, col0 = bn * 128;
    const int t = threadIdx.x, w = t >> 6, l = t & 63;
    const int wr = w >> 1, wc = w & 1;

    f32x4 acc[4][4];
    #pragma unroll
    for (int i = 0; i < 4; ++i)
        #pragma unroll
        for (int j = 0; j < 4; ++j)
            #pragma unroll
            for (int c = 0; c < 4; ++c) acc[i][j][c] = 0.f;

    for (int k0 = 0; k0 < K; k0 += 64) {
        #pragma unroll
        for (int i = 0; i < 4; ++i) {
            int chunk = (w * 4 + i) * 64 + l;
            int r = chunk >> 3, c = chunk & 7;
            int soff = (c ^ (r & 7)) * 8;
            GLOAD16(Ab + (size_t)(row0 + r) * K + k0 + soff, &As[(w * 4 + i) * 512]);
            GLOAD16(Bt + (size_t)(col0 + r) * K + k0 + soff, &Bs[(w * 4 + i) * 512]);
        }
        __syncthreads();

        #pragma unroll
        for (int eks = 0; eks < 2; ++eks) {
            bf16x8 af[4], bfv[4];
            #pragma unroll
            for (int mi = 0; mi < 4; ++mi) {
                int row = wr * 64 + mi * 16 + (l & 15);
                int sl = (eks * 4 + (l >> 4)) ^ (row & 7);
                af[mi] = *(const bf16x8*)&As[row * 64 + sl * 8];
            }
            #pragma unroll
            for (int ni = 0; ni < 4; ++ni) {
                int row = wc * 64 + ni * 16 + (l & 15);
                int sl = (eks * 4 + (l >> 4)) ^ (row & 7);
                bfv[ni] = *(const bf16x8*)&Bs[row * 64 + sl * 8];
            }
            __builtin_amdgcn_s_setprio(1);
            #pragma unroll
            for (int mi = 0; mi < 4; ++mi)
                #pragma unroll
                for (int ni = 0; ni < 4; ++ni)
                    acc[mi][ni] = __builtin_amdgcn_mfma_f32_16x16x32_bf16(
                        af[mi], bfv[ni], acc[mi][ni], 0, 0, 0);
            __builtin_amdgcn_s_setprio(0);
        }
        __syncthreads();
    }

    #pragma unroll
    for (int mi = 0; mi < 4; ++mi)
        #pragma unroll
        for (int ni = 0; ni < 4; ++ni) {
            int col = col0 + wc * 64 + ni * 16 + (l & 15);
            float bv = bias[col];
            int rowb = row0 + wr * 64 + mi * 16 + (l >> 4) * 4;
            if (omode == 2) {
                union { bf16_t h[4]; uint64_t q; } pk;
                #pragma unroll
                for (int j = 0; j < 4; ++j)
                    pk.h[j] = (bf16_t)(acc[mi][ni][j] + bv);
                *(uint64_t*)((bf16_t*)Cv + (size_t)col * M + rowb) = pk.q;
            } else if (omode == 1) {
                #pragma unroll
                for (int j = 0; j < 4; ++j)
                    ((float*)Cv)[(size_t)(rowb + j) * N + col] = acc[mi][ni][j] + bv;
            } else {
                #pragma unroll
                for (int j = 0; j < 4; ++j)
                    ((bf16_t*)Cv)[(size_t)(rowb + j) * N + col] = (bf16_t)(acc[mi][ni][j] + bv);
            }
        }
}

// ---------------------------------------------------------------------------
// Flash attention v5b: fixed-max softmax + split-KV(2) + XCD-affinity remap.
// Fixed max => partials merge LINEARLY: block stores raw sum(P V) (bf16) and
// lsum (f32); merge kernel divides.  S-acc initialized to -M0 (fold subtract
// into MFMA C-input).  P-frag redistribution via VERIFIED shfl_xor+select
// (R3/R4/R6/R7-proven map).  Block map: xcd=bid&7, j=bid>>3:
// bh=xcd*4+(j&3), qb=(j>>2)&15, split=j>>6  (bijective over 1024 blocks).
// ---------------------------------------------------------------------------
__global__ __launch_bounds__(256)
void attn5_kernel(const bf16_t* __restrict__ qp, const bf16_t* __restrict__ kp,
                  const bf16_t* __restrict__ vT,
                  bf16_t* __restrict__ pa0, bf16_t* __restrict__ pa1,
                  float* __restrict__ ls0, float* __restrict__ ls1)
{
    __shared__ bf16_t Ks[2][4096];
    __shared__ bf16_t Vs[2][4096];
    const int bid = blockIdx.x;
    const int xcd = bid & 7, j = bid >> 3;
    const int bh = (xcd << 2) | (j & 3);
    const int qb = (j >> 2) & 15, split = j >> 6;
    const int b = bh >> 4, h = bh & 15;
    const int t = threadIdx.x, w = t >> 6, l = t & 63;
    const int ql = l & 31, hh = l >> 5;
    const float M0 = 8.0f * 1.44269504f;

    bf16_t* pa = split ? pa1 : pa0;
    float*  ls = split ? ls1 : ls0;

    const bf16_t* kbase = kp + ((size_t)b * 2048 + split * 1024) * 1024 + h * 64;
    const bf16_t* vbase = vT + ((size_t)h * 64) * 4096 + (size_t)b * 2048 + split * 1024;
    const int q0 = qb * 128 + w * 32;

    bf16x8 qf[4];
    {
        const bf16_t* qrow = qp + ((size_t)b * 2048 + q0 + ql) * 1024 + h * 64;
        const float qs = 0.125f * 1.44269504f;
        #pragma unroll
        for (int eks = 0; eks < 4; ++eks) {
            bf16x8 v = *(const bf16x8*)(qrow + eks * 16 + hh * 8);
            #pragma unroll
            for (int jj = 0; jj < 8; ++jj) v[jj] = (bf16_t)((float)v[jj] * qs);
            qf[eks] = v;
        }
    }

    f32x16 acc0, acc1;
    #pragma unroll
    for (int r = 0; r < 16; ++r) { acc0[r] = 0.f; acc1[r] = 0.f; }
    float lsum = 0.f;

    const int r0 = t >> 3, r1 = 32 + (t >> 3), g = t & 7;
    const int w0off = r0 * 64 + ((g ^ (r0 & 7)) * 8);
    const int w1off = r1 * 64 + ((g ^ (r1 & 7)) * 8);

    {
        bf16x8 a = *(const bf16x8*)(kbase + (size_t)r0 * 1024 + g * 8);
        bf16x8 c = *(const bf16x8*)(kbase + (size_t)r1 * 1024 + g * 8);
        bf16x8 d = *(const bf16x8*)(vbase + (size_t)r0 * 4096 + g * 8);
        bf16x8 e = *(const bf16x8*)(vbase + (size_t)r1 * 4096 + g * 8);
        *(bf16x8*)&Ks[0][w0off] = a;  *(bf16x8*)&Ks[0][w1off] = c;
        *(bf16x8*)&Vs[0][w0off] = d;  *(bf16x8*)&Vs[0][w1off] = e;
    }
    __syncthreads();

    int cur = 0;
    for (int tile = 0; tile < 16; ++tile) {
        bf16x8 kr0, kr1, vr0, vr1;
        const bool pf = (tile + 1 < 16);
        if (pf) {                           // issue-early (T14)
            const int s1 = (tile + 1) * 64;
            kr0 = *(const bf16x8*)(kbase + (size_t)(s1 + r0) * 1024 + g * 8);
            kr1 = *(const bf16x8*)(kbase + (size_t)(s1 + r1) * 1024 + g * 8);
            vr0 = *(const bf16x8*)(vbase + (size_t)r0 * 4096 + s1 + g * 8);
            vr1 = *(const bf16x8*)(vbase + (size_t)r1 * 4096 + s1 + g * 8);
        }

        // ---- S^T = K Q^T, C-init = -M0 (folds softmax subtract) ----
        f32x16 sA, sB;
        #pragma unroll
        for (int r = 0; r < 16; ++r) { sA[r] = -M0; sB[r] = -M0; }
        __builtin_amdgcn_s_setprio(1);
        #pragma unroll
        for (int eks = 0; eks < 4; ++eks) {
            bf16x8 k0 = *(const bf16x8*)&Ks[cur][ql * 64 + (((2 * eks + hh) ^ (ql & 7)) * 8)];
            bf16x8 k1 = *(const bf16x8*)&Ks[cur][(32 + ql) * 64 + (((2 * eks + hh) ^ (ql & 7)) * 8)];
            sA = __builtin_amdgcn_mfma_f32_32x32x16_bf16(k0, qf[eks], sA, 0, 0, 0);
            sB = __builtin_amdgcn_mfma_f32_32x32x16_bf16(k1, qf[eks], sB, 0, 0, 0);
        }
        __builtin_amdgcn_s_setprio(0);

        // ---- P = exp2(S') directly ----
        uint32_t wA[8], wB[8];
        float rs = 0.f;
        #pragma unroll
        for (int i = 0; i < 8; ++i) {
            float p0 = EXP2F(sA[2 * i]);
            float p1 = EXP2F(sA[2 * i + 1]);
            rs += p0 + p1;  wA[i] = pack2(p0, p1);
            float p2 = EXP2F(sB[2 * i]);
            float p3 = EXP2F(sB[2 * i + 1]);
            rs += p2 + p3;  wB[i] = pack2(p2, p3);
        }
        rs += __shfl_xor(rs, 32);
        lsum += rs;

        // ---- O^T += V^T P^T ; P-frags via verified shfl_xor select ----
        #pragma unroll
        for (int ks = 0; ks < 4; ++ks) {
            const int base = (ks & 1) * 4;
            uint32_t a0 = (ks < 2) ? wA[base]     : wB[base];
            uint32_t a1 = (ks < 2) ? wA[base + 1] : wB[base + 1];
            uint32_t a2 = (ks < 2) ? wA[base + 2] : wB[base + 2];
            uint32_t a3 = (ks < 2) ? wA[base + 3] : wB[base + 3];
            uint32_t x0 = (uint32_t)__shfl_xor((int)a0, 32);
            uint32_t x1 = (uint32_t)__shfl_xor((int)a1, 32);
            uint32_t x2 = (uint32_t)__shfl_xor((int)a2, 32);
            uint32_t x3 = (uint32_t)__shfl_xor((int)a3, 32);
            union { uint32_t u[4]; bf16x8 v; } pb;
            pb.u[0] = hh ? x2 : a0;
            pb.u[1] = hh ? x3 : a1;
            pb.u[2] = hh ? a2 : x0;
            pb.u[3] = hh ? a3 : x1;
            bf16x8 v0 = *(const bf16x8*)&Vs[cur][ql * 64 + (((2 * ks + hh) ^ (ql & 7)) * 8)];
            bf16x8 v1 = *(const bf16x8*)&Vs[cur][(32 + ql) * 64 + (((2 * ks + hh) ^ (ql & 7)) * 8)];
            __builtin_amdgcn_s_setprio(1);
            acc0 = __builtin_amdgcn_mfma_f32_32x32x16_bf16(v0, pb.v, acc0, 0, 0, 0);
            acc1 = __builtin_amdgcn_mfma_f32_32x32x16_bf16(v1, pb.v, acc1, 0, 0, 0);
            __builtin_amdgcn_s_setprio(0);
        }

        if (pf) {                           // write-late
            *(bf16x8*)&Ks[cur ^ 1][w0off] = kr0;
            *(bf16x8*)&Ks[cur ^ 1][w1off] = kr1;
            *(bf16x8*)&Vs[cur ^ 1][w0off] = vr0;
            *(bf16x8*)&Vs[cur ^ 1][w1off] = vr1;
        }
        __syncthreads();
        cur ^= 1;
    }

    // ---- epilogue: store RAW partial O (no normalize) + lsum ----
    bf16_t* sc = &Ks[0][0];
    #pragma unroll
    for (int r = 0; r < 16; ++r) {
        int e = (r & 3) + 8 * (r >> 2) + 4 * hh;
        sc[w * 2048 + ql * 64 + (((e >> 3) ^ (ql & 7)) * 8) + (e & 7)] =
            (bf16_t)acc0[r];
        int e2 = e + 32;
        sc[w * 2048 + ql * 64 + (((e2 >> 3) ^ (ql & 7)) * 8) + (e2 & 7)] =
            (bf16_t)acc1[r];
    }
    if (hh == 0)
        ls[((size_t)b * 2048 + q0 + ql) * 16 + h] = lsum;
    __syncthreads();
    #pragma unroll
    for (int it = 0; it < 4; ++it) {
        int ci = it * 64 + l;
        int qr = ci >> 3, ec = ci & 7;
        bf16x8 ov = *(const bf16x8*)&sc[w * 2048 + qr * 64 + ((ec ^ (qr & 7)) * 8)];
        *(bf16x8*)(pa + ((size_t)b * 2048 + q0 + qr) * 1024 + h * 64 + ec * 8) = ov;
    }
}

// ---------------------------------------------------------------------------
// Merge split-KV partials: ao = (pa0 + pa1) / (ls0 + ls1).  2048 blocks.
// ---------------------------------------------------------------------------
__global__ __launch_bounds__(256)
void merge_kernel(const bf16_t* __restrict__ pa0, const bf16_t* __restrict__ pa1,
                  const float* __restrict__ ls0, const float* __restrict__ ls1,
                  bf16_t* __restrict__ ao)
{
    size_t i0 = ((size_t)blockIdx.x * 256 + threadIdx.x) * 8;
    int row = (int)(i0 >> 10);
    int h = (int)((i0 & 1023) >> 6);
    float inv = 1.0f / (ls0[(size_t)row * 16 + h] + ls1[(size_t)row * 16 + h]);
    bf16x8 a = *(const bf16x8*)(pa0 + i0);
    bf16x8 b = *(const bf16x8*)(pa1 + i0);
    bf16x8 r;
    #pragma unroll
    for (int j = 0; j < 8; ++j)
        r[j] = (bf16_t)(((float)a[j] + (float)b[j]) * inv);
    *(bf16x8*)(ao + i0) = r;
}

// ---------------------------------------------------------------------------
extern "C" void kernel_launch(void* const* d_in, const int* in_sizes, int n_in,
                              void* d_out, int out_size, void* d_ws, size_t ws_size,
                              hipStream_t stream)
{
    const float* Q  = (const float*)d_in[0];
    const float* K  = (const float*)d_in[1];
    const float* V  = (const float*)d_in[2];
    const float* Wq = (const float*)d_in[3];
    const float* bq = (const float*)d_in[4];
    const float* Wk = (const float*)d_in[5];
    const float* bk = (const float*)d_in[6];
    const float* Wv = (const float*)d_in[7];
    const float* bv = (const float*)d_in[8];
    const float* We = (const float*)d_in[9];
    const float* be = (const float*)d_in[10];
    float* out = (float*)d_out;

    bf16_t* ws = (bf16_t*)d_ws;
    bf16_t* WqT = ws;                       // 1M elems each
    bf16_t* WkT = WqT + 1024 * 1024;
    bf16_t* WvT = WkT + 1024 * 1024;
    bf16_t* WeT = WvT + 1024 * 1024;
    bf16_t* qp  = WeT + 1024 * 1024;        // [4096][1024]
    bf16_t* kp  = qp  + 4096 * 1024;        // [4096][1024]
    bf16_t* vt  = kp  + 4096 * 1024;        // [1024][4096] (V proj transposed)
    bf16_t* ao  = vt  + 4096 * 1024;        // [4096][1024]
    bf16_t* Qb  = ao  + 4096 * 1024;        // bf16 input copies
    bf16_t* Kb  = Qb  + 4096 * 1024;
    bf16_t* Vb  = Kb  + 4096 * 1024;        // total 64 MB (R7-proven footprint)

    // Qb/Kb/Vb are dead after the projection GEMM -> reuse for split-KV
    bf16_t* pa0 = Qb;                       // partial O, split 0
    bf16_t* pa1 = Kb;                       // partial O, split 1
    float*  ls0 = (float*)Vb;               // [4096][16] lsums
    float*  ls1 = ls0 + 4096 * 16;

    dim3 blk(256);

    hipLaunchKernelGGL(wtrans_kernel, dim3(16, 16, 4), blk, 0, stream,
                       Wq, Wk, Wv, We, WqT, WkT, WvT, WeT);

    hipLaunchKernelGGL(cvt_kernel, dim3(2048, 3), blk, 0, stream,
                       Q, K, V, Qb, Kb, Vb);

    hipLaunchKernelGGL((gemm3_kernel<true>), dim3(256, 3), blk, 0, stream,
                       Qb, Kb, Vb, WqT, WkT, WvT, bq, bk, bv,
                       (void*)qp, (void*)kp, (void*)vt);

    hipLaunchKernelGGL(attn5_kernel, dim3(1024), blk, 0, stream,
                       qp, kp, vt, pa0, pa1, ls0, ls1);

    hipLaunchKernelGGL(merge_kernel, dim3(2048), blk, 0, stream,
                       pa0, pa1, ls0, ls1, ao);

    hipLaunchKernelGGL((gemm3_kernel<false>), dim3(256, 1), blk, 0, stream,
                       ao, (const bf16_t*)nullptr, (const bf16_t*)nullptr,
                       WeT, (const bf16_t*)nullptr, (const bf16_t*)nullptr,
                       be, (const float*)nullptr, (const float*)nullptr,
                       (void*)out, (void*)nullptr, (void*)nullptr);
}

// Round 10
// 137.952 us; speedup vs baseline: 1.0535x; 1.0535x over previous
//
#include <hip/hip_runtime.h>
#include <hip/hip_bf16.h>
#include <stdint.h>

typedef __bf16 bf16_t;
typedef bf16_t bf16x8 __attribute__((ext_vector_type(8)));
typedef float  f32x4  __attribute__((ext_vector_type(4)));
typedef float  f32x16 __attribute__((ext_vector_type(16)));

#define GLOAD16(gp, lp) __builtin_amdgcn_global_load_lds( \
    (const __attribute__((address_space(1))) void*)(gp),  \
    (__attribute__((address_space(3))) void*)(lp), 16, 0, 0)

#define EXP2F(x) __builtin_amdgcn_exp2f(x)

__device__ inline uint32_t pack2(float lo, float hi) {
    union { bf16_t h[2]; uint32_t u; } x;
    x.h[0] = (bf16_t)lo; x.h[1] = (bf16_t)hi;
    return x.u;
}

// ---------------------------------------------------------------------------
// Weight transpose + fp32->bf16 convert: Wt[n][k] = (bf16) W[k][n], 1024x1024
// ---------------------------------------------------------------------------
__global__ __launch_bounds__(256) void wtrans_kernel(
    const float* __restrict__ Wq, const float* __restrict__ Wk,
    const float* __restrict__ Wv, const float* __restrict__ We,
    bf16_t* __restrict__ WqT, bf16_t* __restrict__ WkT,
    bf16_t* __restrict__ WvT, bf16_t* __restrict__ WeT)
{
    __shared__ bf16_t T[64][65];
    const float* W = (blockIdx.z == 0) ? Wq : (blockIdx.z == 1) ? Wk
                   : (blockIdx.z == 2) ? Wv : We;
    bf16_t* O = (blockIdx.z == 0) ? WqT : (blockIdx.z == 1) ? WkT
              : (blockIdx.z == 2) ? WvT : WeT;
    const int k0 = blockIdx.y * 64, n0 = blockIdx.x * 64;
    const int t = threadIdx.x;
    for (int i = 0; i < 16; ++i) {
        int flat = t + i * 256;
        int r = flat >> 6, c = flat & 63;
        T[r][c] = (bf16_t)W[(size_t)(k0 + r) * 1024 + n0 + c];
    }
    __syncthreads();
    for (int i = 0; i < 16; ++i) {
        int flat = t + i * 256;
        int n = flat >> 6, kk = flat & 63;
        O[(size_t)(n0 + n) * 1024 + k0 + kk] = T[kk][n];
    }
}

// ---------------------------------------------------------------------------
// Streaming fp32 -> bf16 convert for Q, K, V (4096x1024 each).
// ---------------------------------------------------------------------------
__global__ __launch_bounds__(256)
void cvt_kernel(const float* __restrict__ X0, const float* __restrict__ X1,
                const float* __restrict__ X2,
                bf16_t* __restrict__ Y0, bf16_t* __restrict__ Y1,
                bf16_t* __restrict__ Y2)
{
    const float* X = (blockIdx.y == 0) ? X0 : (blockIdx.y == 1) ? X1 : X2;
    bf16_t*      Y = (blockIdx.y == 0) ? Y0 : (blockIdx.y == 1) ? Y1 : Y2;
    size_t i0 = ((size_t)blockIdx.x * 256 + threadIdx.x) * 8;
    float4 v0 = *(const float4*)(X + i0);
    float4 v1 = *(const float4*)(X + i0 + 4);
    bf16x8 pv;
    pv[0] = (bf16_t)v0.x; pv[1] = (bf16_t)v0.y;
    pv[2] = (bf16_t)v0.z; pv[3] = (bf16_t)v0.w;
    pv[4] = (bf16_t)v1.x; pv[5] = (bf16_t)v1.y;
    pv[6] = (bf16_t)v1.z; pv[7] = (bf16_t)v1.w;
    *(bf16x8*)(Y + i0) = pv;
}

// ---------------------------------------------------------------------------
// GEMM v3 (all-bf16, m97-class): C = A @ Bt^T + bias.  M=4096,N=1024,K=1024.
// Both operands via global_load_lds w=16, XOR-swizzle (pre-swz source),
// XCD-locality block remap.  Unchanged (proven R7-R9).
// ---------------------------------------------------------------------------
template<bool BATCHED>
__global__ __launch_bounds__(256)
void gemm3_kernel(const bf16_t* __restrict__ A0, const bf16_t* __restrict__ A1,
                  const bf16_t* __restrict__ A2,
                  const bf16_t* __restrict__ B0, const bf16_t* __restrict__ B1,
                  const bf16_t* __restrict__ B2,
                  const float* __restrict__ b0, const float* __restrict__ b1,
                  const float* __restrict__ b2,
                  void* __restrict__ C0, void* __restrict__ C1,
                  void* __restrict__ C2)
{
    constexpr int M = 4096, K = 1024, N = 1024;
    __shared__ bf16_t As[128 * 64];
    __shared__ bf16_t Bs[128 * 64];

    const int msel = BATCHED ? blockIdx.y : 0;
    const bf16_t* Ab   = (msel == 0) ? A0 : (msel == 1) ? A1 : A2;
    const bf16_t* Bt   = (msel == 0) ? B0 : (msel == 1) ? B1 : B2;
    const float*  bias = (msel == 0) ? b0 : (msel == 1) ? b1 : b2;
    void*         Cv   = (msel == 0) ? C0 : (msel == 1) ? C1 : C2;
    const int omode = BATCHED ? ((msel == 2) ? 2 : 0) : 1;

    const int xcd = blockIdx.x & 7, idx = blockIdx.x >> 3;
    const int bm = (xcd << 2) | (idx >> 3), bn = idx & 7;
    const int row0 = bm * 128, col0 = bn * 128;
    const int t = threadIdx.x, w = t >> 6, l = t & 63;
    const int wr = w >> 1, wc = w & 1;

    f32x4 acc[4][4];
    #pragma unroll
    for (int i = 0; i < 4; ++i)
        #pragma unroll
        for (int j = 0; j < 4; ++j)
            #pragma unroll
            for (int c = 0; c < 4; ++c) acc[i][j][c] = 0.f;

    for (int k0 = 0; k0 < K; k0 += 64) {
        #pragma unroll
        for (int i = 0; i < 4; ++i) {
            int chunk = (w * 4 + i) * 64 + l;
            int r = chunk >> 3, c = chunk & 7;
            int soff = (c ^ (r & 7)) * 8;
            GLOAD16(Ab + (size_t)(row0 + r) * K + k0 + soff, &As[(w * 4 + i) * 512]);
            GLOAD16(Bt + (size_t)(col0 + r) * K + k0 + soff, &Bs[(w * 4 + i) * 512]);
        }
        __syncthreads();

        #pragma unroll
        for (int eks = 0; eks < 2; ++eks) {
            bf16x8 af[4], bfv[4];
            #pragma unroll
            for (int mi = 0; mi < 4; ++mi) {
                int row = wr * 64 + mi * 16 + (l & 15);
                int sl = (eks * 4 + (l >> 4)) ^ (row & 7);
                af[mi] = *(const bf16x8*)&As[row * 64 + sl * 8];
            }
            #pragma unroll
            for (int ni = 0; ni < 4; ++ni) {
                int row = wc * 64 + ni * 16 + (l & 15);
                int sl = (eks * 4 + (l >> 4)) ^ (row & 7);
                bfv[ni] = *(const bf16x8*)&Bs[row * 64 + sl * 8];
            }
            __builtin_amdgcn_s_setprio(1);
            #pragma unroll
            for (int mi = 0; mi < 4; ++mi)
                #pragma unroll
                for (int ni = 0; ni < 4; ++ni)
                    acc[mi][ni] = __builtin_amdgcn_mfma_f32_16x16x32_bf16(
                        af[mi], bfv[ni], acc[mi][ni], 0, 0, 0);
            __builtin_amdgcn_s_setprio(0);
        }
        __syncthreads();
    }

    #pragma unroll
    for (int mi = 0; mi < 4; ++mi)
        #pragma unroll
        for (int ni = 0; ni < 4; ++ni) {
            int col = col0 + wc * 64 + ni * 16 + (l & 15);
            float bv = bias[col];
            int rowb = row0 + wr * 64 + mi * 16 + (l >> 4) * 4;
            if (omode == 2) {
                union { bf16_t h[4]; uint64_t q; } pk;
                #pragma unroll
                for (int j = 0; j < 4; ++j)
                    pk.h[j] = (bf16_t)(acc[mi][ni][j] + bv);
                *(uint64_t*)((bf16_t*)Cv + (size_t)col * M + rowb) = pk.q;
            } else if (omode == 1) {
                #pragma unroll
                for (int j = 0; j < 4; ++j)
                    ((float*)Cv)[(size_t)(rowb + j) * N + col] = acc[mi][ni][j] + bv;
            } else {
                #pragma unroll
                for (int j = 0; j < 4; ++j)
                    ((bf16_t*)Cv)[(size_t)(rowb + j) * N + col] = (bf16_t)(acc[mi][ni][j] + bv);
            }
        }
}

// ---------------------------------------------------------------------------
// Flash attention v6: fixed-max exp2 softmax, C-init=-M0, XCD-affinity map
// (512 blocks: xcd=bid&7, j=bid>>3 -> bh=xcd*4+(j&3), qb=j>>2), and
// K/V staging via global_load_lds w=16 double-buffer (GEMM-proven pattern:
// linear LDS dest, pre-swizzled per-lane global source, barrier drains vm).
// Swapped QK^T / swapped PV, in-register P via verified shfl_xor select.
// ---------------------------------------------------------------------------
__global__ __launch_bounds__(256)
void attn6_kernel(const bf16_t* __restrict__ qp, const bf16_t* __restrict__ kp,
                  const bf16_t* __restrict__ vT, bf16_t* __restrict__ o)
{
    __shared__ bf16_t Ks[2][4096];
    __shared__ bf16_t Vs[2][4096];
    const int bid = blockIdx.x;
    const int xcd = bid & 7, j = bid >> 3;
    const int bh = (xcd << 2) | (j & 3);
    const int qb = j >> 2;
    const int b = bh >> 4, h = bh & 15;
    const int t = threadIdx.x, w = t >> 6, l = t & 63;
    const int ql = l & 31, hh = l >> 5;
    const float M0 = 8.0f * 1.44269504f;

    const bf16_t* kbase = kp + ((size_t)b * 2048) * 1024 + h * 64;
    const bf16_t* vbase = vT + ((size_t)h * 64) * 4096 + (size_t)b * 2048;
    const int q0 = qb * 128 + w * 32;

    bf16x8 qf[4];
    {
        const bf16_t* qrow = qp + ((size_t)b * 2048 + q0 + ql) * 1024 + h * 64;
        const float qs = 0.125f * 1.44269504f;
        #pragma unroll
        for (int eks = 0; eks < 4; ++eks) {
            bf16x8 v = *(const bf16x8*)(qrow + eks * 16 + hh * 8);
            #pragma unroll
            for (int jj = 0; jj < 8; ++jj) v[jj] = (bf16_t)((float)v[jj] * qs);
            qf[eks] = v;
        }
    }

    f32x16 acc0, acc1;
    #pragma unroll
    for (int r = 0; r < 16; ++r) { acc0[r] = 0.f; acc1[r] = 0.f; }
    float lsum = 0.f;

    // gload chunk mapping: wave w stages chunks (w*2+i)*64+l, i=0,1
    const int ci0 = (w * 2) * 64 + l, ci1 = (w * 2 + 1) * 64 + l;
    const int gr0 = ci0 >> 3, gc0 = ci0 & 7, so0 = ((gc0 ^ (gr0 & 7)) * 8);
    const int gr1 = ci1 >> 3, gc1 = ci1 & 7, so1 = ((gc1 ^ (gr1 & 7)) * 8);

    // prologue: stage tile 0 into buf 0
    GLOAD16(kbase + (size_t)gr0 * 1024 + so0, &Ks[0][(w * 2) * 512]);
    GLOAD16(kbase + (size_t)gr1 * 1024 + so1, &Ks[0][(w * 2 + 1) * 512]);
    GLOAD16(vbase + (size_t)gr0 * 4096 + so0, &Vs[0][(w * 2) * 512]);
    GLOAD16(vbase + (size_t)gr1 * 4096 + so1, &Vs[0][(w * 2 + 1) * 512]);
    __syncthreads();

    int cur = 0;
    for (int tile = 0; tile < 32; ++tile) {
        if (tile + 1 < 32) {                 // async prefetch next tile
            const int s1 = (tile + 1) * 64;
            GLOAD16(kbase + (size_t)(s1 + gr0) * 1024 + so0, &Ks[cur ^ 1][(w * 2) * 512]);
            GLOAD16(kbase + (size_t)(s1 + gr1) * 1024 + so1, &Ks[cur ^ 1][(w * 2 + 1) * 512]);
            GLOAD16(vbase + (size_t)gr0 * 4096 + s1 + so0, &Vs[cur ^ 1][(w * 2) * 512]);
            GLOAD16(vbase + (size_t)gr1 * 4096 + s1 + so1, &Vs[cur ^ 1][(w * 2 + 1) * 512]);
        }

        // ---- S^T = K Q^T, C-init = -M0 ----
        f32x16 sA, sB;
        #pragma unroll
        for (int r = 0; r < 16; ++r) { sA[r] = -M0; sB[r] = -M0; }
        __builtin_amdgcn_s_setprio(1);
        #pragma unroll
        for (int eks = 0; eks < 4; ++eks) {
            bf16x8 k0 = *(const bf16x8*)&Ks[cur][ql * 64 + (((2 * eks + hh) ^ (ql & 7)) * 8)];
            bf16x8 k1 = *(const bf16x8*)&Ks[cur][(32 + ql) * 64 + (((2 * eks + hh) ^ (ql & 7)) * 8)];
            sA = __builtin_amdgcn_mfma_f32_32x32x16_bf16(k0, qf[eks], sA, 0, 0, 0);
            sB = __builtin_amdgcn_mfma_f32_32x32x16_bf16(k1, qf[eks], sB, 0, 0, 0);
        }
        __builtin_amdgcn_s_setprio(0);

        // ---- P = exp2(S') ----
        uint32_t wA[8], wB[8];
        float rs = 0.f;
        #pragma unroll
        for (int i = 0; i < 8; ++i) {
            float p0 = EXP2F(sA[2 * i]);
            float p1 = EXP2F(sA[2 * i + 1]);
            rs += p0 + p1;  wA[i] = pack2(p0, p1);
            float p2 = EXP2F(sB[2 * i]);
            float p3 = EXP2F(sB[2 * i + 1]);
            rs += p2 + p3;  wB[i] = pack2(p2, p3);
        }
        rs += __shfl_xor(rs, 32);
        lsum += rs;

        // ---- O^T += V^T P^T ; P-frags via verified shfl_xor select ----
        #pragma unroll
        for (int ks = 0; ks < 4; ++ks) {
            const int base = (ks & 1) * 4;
            uint32_t a0 = (ks < 2) ? wA[base]     : wB[base];
            uint32_t a1 = (ks < 2) ? wA[base + 1] : wB[base + 1];
            uint32_t a2 = (ks < 2) ? wA[base + 2] : wB[base + 2];
            uint32_t a3 = (ks < 2) ? wA[base + 3] : wB[base + 3];
            uint32_t x0 = (uint32_t)__shfl_xor((int)a0, 32);
            uint32_t x1 = (uint32_t)__shfl_xor((int)a1, 32);
            uint32_t x2 = (uint32_t)__shfl_xor((int)a2, 32);
            uint32_t x3 = (uint32_t)__shfl_xor((int)a3, 32);
            union { uint32_t u[4]; bf16x8 v; } pb;
            pb.u[0] = hh ? x2 : a0;
            pb.u[1] = hh ? x3 : a1;
            pb.u[2] = hh ? a2 : x0;
            pb.u[3] = hh ? a3 : x1;
            bf16x8 v0 = *(const bf16x8*)&Vs[cur][ql * 64 + (((2 * ks + hh) ^ (ql & 7)) * 8)];
            bf16x8 v1 = *(const bf16x8*)&Vs[cur][(32 + ql) * 64 + (((2 * ks + hh) ^ (ql & 7)) * 8)];
            __builtin_amdgcn_s_setprio(1);
            acc0 = __builtin_amdgcn_mfma_f32_32x32x16_bf16(v0, pb.v, acc0, 0, 0, 0);
            acc1 = __builtin_amdgcn_mfma_f32_32x32x16_bf16(v1, pb.v, acc1, 0, 0, 0);
            __builtin_amdgcn_s_setprio(0);
        }

        __syncthreads();                     // drains gloads + LDS reads
        cur ^= 1;
    }

    // ---- epilogue: normalize, transpose O^T->O via per-wave swizzled LDS ----
    bf16_t* sc = &Ks[0][0];
    const float inv = 1.0f / lsum;
    #pragma unroll
    for (int r = 0; r < 16; ++r) {
        int e = (r & 3) + 8 * (r >> 2) + 4 * hh;
        sc[w * 2048 + ql * 64 + (((e >> 3) ^ (ql & 7)) * 8) + (e & 7)] =
            (bf16_t)(acc0[r] * inv);
        int e2 = e + 32;
        sc[w * 2048 + ql * 64 + (((e2 >> 3) ^ (ql & 7)) * 8) + (e2 & 7)] =
            (bf16_t)(acc1[r] * inv);
    }
    __syncthreads();
    #pragma unroll
    for (int it = 0; it < 4; ++it) {
        int ci = it * 64 + l;
        int qr = ci >> 3, ec = ci & 7;
        bf16x8 ov = *(const bf16x8*)&sc[w * 2048 + qr * 64 + ((ec ^ (qr & 7)) * 8)];
        *(bf16x8*)(o + ((size_t)b * 2048 + q0 + qr) * 1024 + h * 64 + ec * 8) = ov;
    }
}

// ---------------------------------------------------------------------------
extern "C" void kernel_launch(void* const* d_in, const int* in_sizes, int n_in,
                              void* d_out, int out_size, void* d_ws, size_t ws_size,
                              hipStream_t stream)
{
    const float* Q  = (const float*)d_in[0];
    const float* K  = (const float*)d_in[1];
    const float* V  = (const float*)d_in[2];
    const float* Wq = (const float*)d_in[3];
    const float* bq = (const float*)d_in[4];
    const float* Wk = (const float*)d_in[5];
    const float* bk = (const float*)d_in[6];
    const float* Wv = (const float*)d_in[7];
    const float* bv = (const float*)d_in[8];
    const float* We = (const float*)d_in[9];
    const float* be = (const float*)d_in[10];
    float* out = (float*)d_out;

    bf16_t* ws = (bf16_t*)d_ws;
    bf16_t* WqT = ws;                       // 1M elems each
    bf16_t* WkT = WqT + 1024 * 1024;
    bf16_t* WvT = WkT + 1024 * 1024;
    bf16_t* WeT = WvT + 1024 * 1024;
    bf16_t* qp  = WeT + 1024 * 1024;        // [4096][1024]
    bf16_t* kp  = qp  + 4096 * 1024;        // [4096][1024]
    bf16_t* vt  = kp  + 4096 * 1024;        // [1024][4096] (V proj transposed)
    bf16_t* ao  = vt  + 4096 * 1024;        // [4096][1024]
    bf16_t* Qb  = ao  + 4096 * 1024;        // bf16 input copies
    bf16_t* Kb  = Qb  + 4096 * 1024;
    bf16_t* Vb  = Kb  + 4096 * 1024;        // 64 MB total (proven footprint)

    dim3 blk(256);

    hipLaunchKernelGGL(wtrans_kernel, dim3(16, 16, 4), blk, 0, stream,
                       Wq, Wk, Wv, We, WqT, WkT, WvT, WeT);

    hipLaunchKernelGGL(cvt_kernel, dim3(2048, 3), blk, 0, stream,
                       Q, K, V, Qb, Kb, Vb);

    hipLaunchKernelGGL((gemm3_kernel<true>), dim3(256, 3), blk, 0, stream,
                       Qb, Kb, Vb, WqT, WkT, WvT, bq, bk, bv,
                       (void*)qp, (void*)kp, (void*)vt);

    hipLaunchKernelGGL(attn6_kernel, dim3(512), blk, 0, stream,
                       qp, kp, vt, ao);

    hipLaunchKernelGGL((gemm3_kernel<false>), dim3(256, 1), blk, 0, stream,
                       ao, (const bf16_t*)nullptr, (const bf16_t*)nullptr,
                       WeT, (const bf16_t*)nullptr, (const bf16_t*)nullptr,
                       be, (const float*)nullptr, (const float*)nullptr,
                       (void*)out, (void*)nullptr, (void*)nullptr);
}

// Round 11
// 135.349 us; speedup vs baseline: 1.0738x; 1.0192x over previous
//
#include <hip/hip_runtime.h>
#include <hip/hip_bf16.h>
#include <stdint.h>

typedef __bf16 bf16_t;
typedef bf16_t bf16x8 __attribute__((ext_vector_type(8)));
typedef float  f32x4  __attribute__((ext_vector_type(4)));
typedef float  f32x16 __attribute__((ext_vector_type(16)));

#define GLOAD16(gp, lp) __builtin_amdgcn_global_load_lds( \
    (const __attribute__((address_space(1))) void*)(gp),  \
    (__attribute__((address_space(3))) void*)(lp), 16, 0, 0)

#define EXP2F(x) __builtin_amdgcn_exp2f(x)

__device__ inline uint32_t pack2(float lo, float hi) {
    union { bf16_t h[2]; uint32_t u; } x;
    x.h[0] = (bf16_t)lo; x.h[1] = (bf16_t)hi;
    return x.u;
}

// ---------------------------------------------------------------------------
// Weight transpose + fp32->bf16 convert: Wt[n][k] = (bf16) W[k][n], 1024x1024
// ---------------------------------------------------------------------------
__global__ __launch_bounds__(256) void wtrans_kernel(
    const float* __restrict__ Wq, const float* __restrict__ Wk,
    const float* __restrict__ Wv, const float* __restrict__ We,
    bf16_t* __restrict__ WqT, bf16_t* __restrict__ WkT,
    bf16_t* __restrict__ WvT, bf16_t* __restrict__ WeT)
{
    __shared__ bf16_t T[64][65];
    const float* W = (blockIdx.z == 0) ? Wq : (blockIdx.z == 1) ? Wk
                   : (blockIdx.z == 2) ? Wv : We;
    bf16_t* O = (blockIdx.z == 0) ? WqT : (blockIdx.z == 1) ? WkT
              : (blockIdx.z == 2) ? WvT : WeT;
    const int k0 = blockIdx.y * 64, n0 = blockIdx.x * 64;
    const int t = threadIdx.x;
    for (int i = 0; i < 16; ++i) {
        int flat = t + i * 256;
        int r = flat >> 6, c = flat & 63;
        T[r][c] = (bf16_t)W[(size_t)(k0 + r) * 1024 + n0 + c];
    }
    __syncthreads();
    for (int i = 0; i < 16; ++i) {
        int flat = t + i * 256;
        int n = flat >> 6, kk = flat & 63;
        O[(size_t)(n0 + n) * 1024 + k0 + kk] = T[kk][n];
    }
}

// ---------------------------------------------------------------------------
// Streaming fp32 -> bf16 convert for Q, K, V (4096x1024 each).
// ---------------------------------------------------------------------------
__global__ __launch_bounds__(256)
void cvt_kernel(const float* __restrict__ X0, const float* __restrict__ X1,
                const float* __restrict__ X2,
                bf16_t* __restrict__ Y0, bf16_t* __restrict__ Y1,
                bf16_t* __restrict__ Y2)
{
    const float* X = (blockIdx.y == 0) ? X0 : (blockIdx.y == 1) ? X1 : X2;
    bf16_t*      Y = (blockIdx.y == 0) ? Y0 : (blockIdx.y == 1) ? Y1 : Y2;
    size_t i0 = ((size_t)blockIdx.x * 256 + threadIdx.x) * 8;
    float4 v0 = *(const float4*)(X + i0);
    float4 v1 = *(const float4*)(X + i0 + 4);
    bf16x8 pv;
    pv[0] = (bf16_t)v0.x; pv[1] = (bf16_t)v0.y;
    pv[2] = (bf16_t)v0.z; pv[3] = (bf16_t)v0.w;
    pv[4] = (bf16_t)v1.x; pv[5] = (bf16_t)v1.y;
    pv[6] = (bf16_t)v1.z; pv[7] = (bf16_t)v1.w;
    *(bf16x8*)(Y + i0) = pv;
}

// ---------------------------------------------------------------------------
// GEMM v3 (all-bf16, m97-class): C = A @ Bt^T + bias.  M=4096,N=1024,K=1024.
// Both operands via global_load_lds w=16, XOR-swizzle (pre-swz source),
// XCD-locality block remap.  Unchanged (proven R7-R10).
// ---------------------------------------------------------------------------
template<bool BATCHED>
__global__ __launch_bounds__(256)
void gemm3_kernel(const bf16_t* __restrict__ A0, const bf16_t* __restrict__ A1,
                  const bf16_t* __restrict__ A2,
                  const bf16_t* __restrict__ B0, const bf16_t* __restrict__ B1,
                  const bf16_t* __restrict__ B2,
                  const float* __restrict__ b0, const float* __restrict__ b1,
                  const float* __restrict__ b2,
                  void* __restrict__ C0, void* __restrict__ C1,
                  void* __restrict__ C2)
{
    constexpr int M = 4096, K = 1024, N = 1024;
    __shared__ bf16_t As[128 * 64];
    __shared__ bf16_t Bs[128 * 64];

    const int msel = BATCHED ? blockIdx.y : 0;
    const bf16_t* Ab   = (msel == 0) ? A0 : (msel == 1) ? A1 : A2;
    const bf16_t* Bt   = (msel == 0) ? B0 : (msel == 1) ? B1 : B2;
    const float*  bias = (msel == 0) ? b0 : (msel == 1) ? b1 : b2;
    void*         Cv   = (msel == 0) ? C0 : (msel == 1) ? C1 : C2;
    const int omode = BATCHED ? ((msel == 2) ? 2 : 0) : 1;

    const int xcd = blockIdx.x & 7, idx = blockIdx.x >> 3;
    const int bm = (xcd << 2) | (idx >> 3), bn = idx & 7;
    const int row0 = bm * 128, col0 = bn * 128;
    const int t = threadIdx.x, w = t >> 6, l = t & 63;
    const int wr = w >> 1, wc = w & 1;

    f32x4 acc[4][4];
    #pragma unroll
    for (int i = 0; i < 4; ++i)
        #pragma unroll
        for (int j = 0; j < 4; ++j)
            #pragma unroll
            for (int c = 0; c < 4; ++c) acc[i][j][c] = 0.f;

    for (int k0 = 0; k0 < K; k0 += 64) {
        #pragma unroll
        for (int i = 0; i < 4; ++i) {
            int chunk = (w * 4 + i) * 64 + l;
            int r = chunk >> 3, c = chunk & 7;
            int soff = (c ^ (r & 7)) * 8;
            GLOAD16(Ab + (size_t)(row0 + r) * K + k0 + soff, &As[(w * 4 + i) * 512]);
            GLOAD16(Bt + (size_t)(col0 + r) * K + k0 + soff, &Bs[(w * 4 + i) * 512]);
        }
        __syncthreads();

        #pragma unroll
        for (int eks = 0; eks < 2; ++eks) {
            bf16x8 af[4], bfv[4];
            #pragma unroll
            for (int mi = 0; mi < 4; ++mi) {
                int row = wr * 64 + mi * 16 + (l & 15);
                int sl = (eks * 4 + (l >> 4)) ^ (row & 7);
                af[mi] = *(const bf16x8*)&As[row * 64 + sl * 8];
            }
            #pragma unroll
            for (int ni = 0; ni < 4; ++ni) {
                int row = wc * 64 + ni * 16 + (l & 15);
                int sl = (eks * 4 + (l >> 4)) ^ (row & 7);
                bfv[ni] = *(const bf16x8*)&Bs[row * 64 + sl * 8];
            }
            __builtin_amdgcn_s_setprio(1);
            #pragma unroll
            for (int mi = 0; mi < 4; ++mi)
                #pragma unroll
                for (int ni = 0; ni < 4; ++ni)
                    acc[mi][ni] = __builtin_amdgcn_mfma_f32_16x16x32_bf16(
                        af[mi], bfv[ni], acc[mi][ni], 0, 0, 0);
            __builtin_amdgcn_s_setprio(0);
        }
        __syncthreads();
    }

    #pragma unroll
    for (int mi = 0; mi < 4; ++mi)
        #pragma unroll
        for (int ni = 0; ni < 4; ++ni) {
            int col = col0 + wc * 64 + ni * 16 + (l & 15);
            float bv = bias[col];
            int rowb = row0 + wr * 64 + mi * 16 + (l >> 4) * 4;
            if (omode == 2) {
                union { bf16_t h[4]; uint64_t q; } pk;
                #pragma unroll
                for (int j = 0; j < 4; ++j)
                    pk.h[j] = (bf16_t)(acc[mi][ni][j] + bv);
                *(uint64_t*)((bf16_t*)Cv + (size_t)col * M + rowb) = pk.q;
            } else if (omode == 1) {
                #pragma unroll
                for (int j = 0; j < 4; ++j)
                    ((float*)Cv)[(size_t)(rowb + j) * N + col] = acc[mi][ni][j] + bv;
            } else {
                #pragma unroll
                for (int j = 0; j < 4; ++j)
                    ((bf16_t*)Cv)[(size_t)(rowb + j) * N + col] = (bf16_t)(acc[mi][ni][j] + bv);
            }
        }
}

// ---------------------------------------------------------------------------
// Flash attention v7 = v6 with the P-redistribution done by
// v_permlane32_swap_b32 instead of 16 ds_bpermute + 16 cndmask.
// ISA semantics: swap(vdst, vsrc) -> vdst=[vdst.lo, vsrc.lo],
// vsrc=[vdst.hi, vsrc.hi].  swap(a0,a2): a0 becomes u[0] (lanes<32 own a0,
// lanes>=32 get a2 from lane-32), a2 becomes u[2] -- element-identical to
// the R3-R10-verified shfl_xor select (R8 failed with operands REVERSED).
// ---------------------------------------------------------------------------
__global__ __launch_bounds__(256)
void attn7_kernel(const bf16_t* __restrict__ qp, const bf16_t* __restrict__ kp,
                  const bf16_t* __restrict__ vT, bf16_t* __restrict__ o)
{
    __shared__ bf16_t Ks[2][4096];
    __shared__ bf16_t Vs[2][4096];
    const int bid = blockIdx.x;
    const int xcd = bid & 7, j = bid >> 3;
    const int bh = (xcd << 2) | (j & 3);
    const int qb = j >> 2;
    const int b = bh >> 4, h = bh & 15;
    const int t = threadIdx.x, w = t >> 6, l = t & 63;
    const int ql = l & 31, hh = l >> 5;
    const float M0 = 8.0f * 1.44269504f;

    const bf16_t* kbase = kp + ((size_t)b * 2048) * 1024 + h * 64;
    const bf16_t* vbase = vT + ((size_t)h * 64) * 4096 + (size_t)b * 2048;
    const int q0 = qb * 128 + w * 32;

    bf16x8 qf[4];
    {
        const bf16_t* qrow = qp + ((size_t)b * 2048 + q0 + ql) * 1024 + h * 64;
        const float qs = 0.125f * 1.44269504f;
        #pragma unroll
        for (int eks = 0; eks < 4; ++eks) {
            bf16x8 v = *(const bf16x8*)(qrow + eks * 16 + hh * 8);
            #pragma unroll
            for (int jj = 0; jj < 8; ++jj) v[jj] = (bf16_t)((float)v[jj] * qs);
            qf[eks] = v;
        }
    }

    f32x16 acc0, acc1;
    #pragma unroll
    for (int r = 0; r < 16; ++r) { acc0[r] = 0.f; acc1[r] = 0.f; }
    float lsum = 0.f;

    const int ci0 = (w * 2) * 64 + l, ci1 = (w * 2 + 1) * 64 + l;
    const int gr0 = ci0 >> 3, gc0 = ci0 & 7, so0 = ((gc0 ^ (gr0 & 7)) * 8);
    const int gr1 = ci1 >> 3, gc1 = ci1 & 7, so1 = ((gc1 ^ (gr1 & 7)) * 8);

    GLOAD16(kbase + (size_t)gr0 * 1024 + so0, &Ks[0][(w * 2) * 512]);
    GLOAD16(kbase + (size_t)gr1 * 1024 + so1, &Ks[0][(w * 2 + 1) * 512]);
    GLOAD16(vbase + (size_t)gr0 * 4096 + so0, &Vs[0][(w * 2) * 512]);
    GLOAD16(vbase + (size_t)gr1 * 4096 + so1, &Vs[0][(w * 2 + 1) * 512]);
    __syncthreads();

    int cur = 0;
    for (int tile = 0; tile < 32; ++tile) {
        if (tile + 1 < 32) {                 // async prefetch next tile
            const int s1 = (tile + 1) * 64;
            GLOAD16(kbase + (size_t)(s1 + gr0) * 1024 + so0, &Ks[cur ^ 1][(w * 2) * 512]);
            GLOAD16(kbase + (size_t)(s1 + gr1) * 1024 + so1, &Ks[cur ^ 1][(w * 2 + 1) * 512]);
            GLOAD16(vbase + (size_t)gr0 * 4096 + s1 + so0, &Vs[cur ^ 1][(w * 2) * 512]);
            GLOAD16(vbase + (size_t)gr1 * 4096 + s1 + so1, &Vs[cur ^ 1][(w * 2 + 1) * 512]);
        }

        // ---- S^T = K Q^T, C-init = -M0 ----
        f32x16 sA, sB;
        #pragma unroll
        for (int r = 0; r < 16; ++r) { sA[r] = -M0; sB[r] = -M0; }
        __builtin_amdgcn_s_setprio(1);
        #pragma unroll
        for (int eks = 0; eks < 4; ++eks) {
            bf16x8 k0 = *(const bf16x8*)&Ks[cur][ql * 64 + (((2 * eks + hh) ^ (ql & 7)) * 8)];
            bf16x8 k1 = *(const bf16x8*)&Ks[cur][(32 + ql) * 64 + (((2 * eks + hh) ^ (ql & 7)) * 8)];
            sA = __builtin_amdgcn_mfma_f32_32x32x16_bf16(k0, qf[eks], sA, 0, 0, 0);
            sB = __builtin_amdgcn_mfma_f32_32x32x16_bf16(k1, qf[eks], sB, 0, 0, 0);
        }
        __builtin_amdgcn_s_setprio(0);

        // ---- P = exp2(S') ----
        uint32_t wA[8], wB[8];
        float rs = 0.f;
        #pragma unroll
        for (int i = 0; i < 8; ++i) {
            float p0 = EXP2F(sA[2 * i]);
            float p1 = EXP2F(sA[2 * i + 1]);
            rs += p0 + p1;  wA[i] = pack2(p0, p1);
            float p2 = EXP2F(sB[2 * i]);
            float p3 = EXP2F(sB[2 * i + 1]);
            rs += p2 + p3;  wB[i] = pack2(p2, p3);
        }
        rs += __shfl_xor(rs, 32);
        lsum += rs;

        // ---- O^T += V^T P^T ; P-frags via permlane32_swap (correct dir) ----
        #pragma unroll
        for (int ks = 0; ks < 4; ++ks) {
            const int base = (ks & 1) * 4;
            uint32_t a0 = (ks < 2) ? wA[base]     : wB[base];
            uint32_t a1 = (ks < 2) ? wA[base + 1] : wB[base + 1];
            uint32_t a2 = (ks < 2) ? wA[base + 2] : wB[base + 2];
            uint32_t a3 = (ks < 2) ? wA[base + 3] : wB[base + 3];
            // swap(vdst=a0, vsrc=a2): a0=[a0.lo,a2.lo]=u[0], a2=[a0.hi,a2.hi]=u[2]
            asm volatile("v_permlane32_swap_b32 %0, %1" : "+v"(a0), "+v"(a2));
            asm volatile("v_permlane32_swap_b32 %0, %1" : "+v"(a1), "+v"(a3));
            union { uint32_t u[4]; bf16x8 v; } pb;
            pb.u[0] = a0; pb.u[1] = a1; pb.u[2] = a2; pb.u[3] = a3;
            bf16x8 v0 = *(const bf16x8*)&Vs[cur][ql * 64 + (((2 * ks + hh) ^ (ql & 7)) * 8)];
            bf16x8 v1 = *(const bf16x8*)&Vs[cur][(32 + ql) * 64 + (((2 * ks + hh) ^ (ql & 7)) * 8)];
            __builtin_amdgcn_s_setprio(1);
            acc0 = __builtin_amdgcn_mfma_f32_32x32x16_bf16(v0, pb.v, acc0, 0, 0, 0);
            acc1 = __builtin_amdgcn_mfma_f32_32x32x16_bf16(v1, pb.v, acc1, 0, 0, 0);
            __builtin_amdgcn_s_setprio(0);
        }

        __syncthreads();
        cur ^= 1;
    }

    // ---- epilogue: normalize, transpose O^T->O via per-wave swizzled LDS ----
    bf16_t* sc = &Ks[0][0];
    const float inv = 1.0f / lsum;
    #pragma unroll
    for (int r = 0; r < 16; ++r) {
        int e = (r & 3) + 8 * (r >> 2) + 4 * hh;
        sc[w * 2048 + ql * 64 + (((e >> 3) ^ (ql & 7)) * 8) + (e & 7)] =
            (bf16_t)(acc0[r] * inv);
        int e2 = e + 32;
        sc[w * 2048 + ql * 64 + (((e2 >> 3) ^ (ql & 7)) * 8) + (e2 & 7)] =
            (bf16_t)(acc1[r] * inv);
    }
    __syncthreads();
    #pragma unroll
    for (int it = 0; it < 4; ++it) {
        int ci = it * 64 + l;
        int qr = ci >> 3, ec = ci & 7;
        bf16x8 ov = *(const bf16x8*)&sc[w * 2048 + qr * 64 + ((ec ^ (qr & 7)) * 8)];
        *(bf16x8*)(o + ((size_t)b * 2048 + q0 + qr) * 1024 + h * 64 + ec * 8) = ov;
    }
}

// ---------------------------------------------------------------------------
extern "C" void kernel_launch(void* const* d_in, const int* in_sizes, int n_in,
                              void* d_out, int out_size, void* d_ws, size_t ws_size,
                              hipStream_t stream)
{
    const float* Q  = (const float*)d_in[0];
    const float* K  = (const float*)d_in[1];
    const float* V  = (const float*)d_in[2];
    const float* Wq = (const float*)d_in[3];
    const float* bq = (const float*)d_in[4];
    const float* Wk = (const float*)d_in[5];
    const float* bk = (const float*)d_in[6];
    const float* Wv = (const float*)d_in[7];
    const float* bv = (const float*)d_in[8];
    const float* We = (const float*)d_in[9];
    const float* be = (const float*)d_in[10];
    float* out = (float*)d_out;

    bf16_t* ws = (bf16_t*)d_ws;
    bf16_t* WqT = ws;                       // 1M elems each
    bf16_t* WkT = WqT + 1024 * 1024;
    bf16_t* WvT = WkT + 1024 * 1024;
    bf16_t* WeT = WvT + 1024 * 1024;
    bf16_t* qp  = WeT + 1024 * 1024;        // [4096][1024]
    bf16_t* kp  = qp  + 4096 * 1024;        // [4096][1024]
    bf16_t* vt  = kp  + 4096 * 1024;        // [1024][4096] (V proj transposed)
    bf16_t* ao  = vt  + 4096 * 1024;        // [4096][1024]
    bf16_t* Qb  = ao  + 4096 * 1024;        // bf16 input copies
    bf16_t* Kb  = Qb  + 4096 * 1024;
    bf16_t* Vb  = Kb  + 4096 * 1024;        // 64 MB total (proven footprint)

    dim3 blk(256);

    hipLaunchKernelGGL(wtrans_kernel, dim3(16, 16, 4), blk, 0, stream,
                       Wq, Wk, Wv, We, WqT, WkT, WvT, WeT);

    hipLaunchKernelGGL(cvt_kernel, dim3(2048, 3), blk, 0, stream,
                       Q, K, V, Qb, Kb, Vb);

    hipLaunchKernelGGL((gemm3_kernel<true>), dim3(256, 3), blk, 0, stream,
                       Qb, Kb, Vb, WqT, WkT, WvT, bq, bk, bv,
                       (void*)qp, (void*)kp, (void*)vt);

    hipLaunchKernelGGL(attn7_kernel, dim3(512), blk, 0, stream,
                       qp, kp, vt, ao);

    hipLaunchKernelGGL((gemm3_kernel<false>), dim3(256, 1), blk, 0, stream,
                       ao, (const bf16_t*)nullptr, (const bf16_t*)nullptr,
                       WeT, (const bf16_t*)nullptr, (const bf16_t*)nullptr,
                       be, (const float*)nullptr, (const float*)nullptr,
                       (void*)out, (void*)nullptr, (void*)nullptr);
}

// Round 12
// 134.516 us; speedup vs baseline: 1.0805x; 1.0062x over previous
//
#include <hip/hip_runtime.h>
#include <hip/hip_bf16.h>
#include <stdint.h>

typedef __bf16 bf16_t;
typedef bf16_t bf16x8 __attribute__((ext_vector_type(8)));
typedef float  f32x4  __attribute__((ext_vector_type(4)));
typedef float  f32x16 __attribute__((ext_vector_type(16)));

#define GLOAD16(gp, lp) __builtin_amdgcn_global_load_lds( \
    (const __attribute__((address_space(1))) void*)(gp),  \
    (__attribute__((address_space(3))) void*)(lp), 16, 0, 0)

#define EXP2F(x) __builtin_amdgcn_exp2f(x)

__device__ inline uint32_t pack2(float lo, float hi) {
    union { bf16_t h[2]; uint32_t u; } x;
    x.h[0] = (bf16_t)lo; x.h[1] = (bf16_t)hi;
    return x.u;
}

// ---------------------------------------------------------------------------
// Weight transpose + fp32->bf16 convert: Wt[n][k] = (bf16) W[k][n], 1024x1024
// ---------------------------------------------------------------------------
__global__ __launch_bounds__(256) void wtrans_kernel(
    const float* __restrict__ Wq, const float* __restrict__ Wk,
    const float* __restrict__ Wv, const float* __restrict__ We,
    bf16_t* __restrict__ WqT, bf16_t* __restrict__ WkT,
    bf16_t* __restrict__ WvT, bf16_t* __restrict__ WeT)
{
    __shared__ bf16_t T[64][65];
    const float* W = (blockIdx.z == 0) ? Wq : (blockIdx.z == 1) ? Wk
                   : (blockIdx.z == 2) ? Wv : We;
    bf16_t* O = (blockIdx.z == 0) ? WqT : (blockIdx.z == 1) ? WkT
              : (blockIdx.z == 2) ? WvT : WeT;
    const int k0 = blockIdx.y * 64, n0 = blockIdx.x * 64;
    const int t = threadIdx.x;
    for (int i = 0; i < 16; ++i) {
        int flat = t + i * 256;
        int r = flat >> 6, c = flat & 63;
        T[r][c] = (bf16_t)W[(size_t)(k0 + r) * 1024 + n0 + c];
    }
    __syncthreads();
    for (int i = 0; i < 16; ++i) {
        int flat = t + i * 256;
        int n = flat >> 6, kk = flat & 63;
        O[(size_t)(n0 + n) * 1024 + k0 + kk] = T[kk][n];
    }
}

// ---------------------------------------------------------------------------
// Streaming fp32 -> bf16 convert for Q, K, V (4096x1024 each).
// ---------------------------------------------------------------------------
__global__ __launch_bounds__(256)
void cvt_kernel(const float* __restrict__ X0, const float* __restrict__ X1,
                const float* __restrict__ X2,
                bf16_t* __restrict__ Y0, bf16_t* __restrict__ Y1,
                bf16_t* __restrict__ Y2)
{
    const float* X = (blockIdx.y == 0) ? X0 : (blockIdx.y == 1) ? X1 : X2;
    bf16_t*      Y = (blockIdx.y == 0) ? Y0 : (blockIdx.y == 1) ? Y1 : Y2;
    size_t i0 = ((size_t)blockIdx.x * 256 + threadIdx.x) * 8;
    float4 v0 = *(const float4*)(X + i0);
    float4 v1 = *(const float4*)(X + i0 + 4);
    bf16x8 pv;
    pv[0] = (bf16_t)v0.x; pv[1] = (bf16_t)v0.y;
    pv[2] = (bf16_t)v0.z; pv[3] = (bf16_t)v0.w;
    pv[4] = (bf16_t)v1.x; pv[5] = (bf16_t)v1.y;
    pv[6] = (bf16_t)v1.z; pv[7] = (bf16_t)v1.w;
    *(bf16x8*)(Y + i0) = pv;
}

// ---------------------------------------------------------------------------
// GEMM v3 (all-bf16, m97-class): C = A @ Bt^T + bias.  M=4096,N=1024,K=1024.
// Both operands via global_load_lds w=16, XOR-swizzle (pre-swz source),
// XCD-locality block remap.  Unchanged (proven R7-R11).
// ---------------------------------------------------------------------------
template<bool BATCHED>
__global__ __launch_bounds__(256)
void gemm3_kernel(const bf16_t* __restrict__ A0, const bf16_t* __restrict__ A1,
                  const bf16_t* __restrict__ A2,
                  const bf16_t* __restrict__ B0, const bf16_t* __restrict__ B1,
                  const bf16_t* __restrict__ B2,
                  const float* __restrict__ b0, const float* __restrict__ b1,
                  const float* __restrict__ b2,
                  void* __restrict__ C0, void* __restrict__ C1,
                  void* __restrict__ C2)
{
    constexpr int M = 4096, K = 1024, N = 1024;
    __shared__ bf16_t As[128 * 64];
    __shared__ bf16_t Bs[128 * 64];

    const int msel = BATCHED ? blockIdx.y : 0;
    const bf16_t* Ab   = (msel == 0) ? A0 : (msel == 1) ? A1 : A2;
    const bf16_t* Bt   = (msel == 0) ? B0 : (msel == 1) ? B1 : B2;
    const float*  bias = (msel == 0) ? b0 : (msel == 1) ? b1 : b2;
    void*         Cv   = (msel == 0) ? C0 : (msel == 1) ? C1 : C2;
    const int omode = BATCHED ? ((msel == 2) ? 2 : 0) : 1;

    const int xcd = blockIdx.x & 7, idx = blockIdx.x >> 3;
    const int bm = (xcd << 2) | (idx >> 3), bn = idx & 7;
    const int row0 = bm * 128, col0 = bn * 128;
    const int t = threadIdx.x, w = t >> 6, l = t & 63;
    const int wr = w >> 1, wc = w & 1;

    f32x4 acc[4][4];
    #pragma unroll
    for (int i = 0; i < 4; ++i)
        #pragma unroll
        for (int j = 0; j < 4; ++j)
            #pragma unroll
            for (int c = 0; c < 4; ++c) acc[i][j][c] = 0.f;

    for (int k0 = 0; k0 < K; k0 += 64) {
        #pragma unroll
        for (int i = 0; i < 4; ++i) {
            int chunk = (w * 4 + i) * 64 + l;
            int r = chunk >> 3, c = chunk & 7;
            int soff = (c ^ (r & 7)) * 8;
            GLOAD16(Ab + (size_t)(row0 + r) * K + k0 + soff, &As[(w * 4 + i) * 512]);
            GLOAD16(Bt + (size_t)(col0 + r) * K + k0 + soff, &Bs[(w * 4 + i) * 512]);
        }
        __syncthreads();

        #pragma unroll
        for (int eks = 0; eks < 2; ++eks) {
            bf16x8 af[4], bfv[4];
            #pragma unroll
            for (int mi = 0; mi < 4; ++mi) {
                int row = wr * 64 + mi * 16 + (l & 15);
                int sl = (eks * 4 + (l >> 4)) ^ (row & 7);
                af[mi] = *(const bf16x8*)&As[row * 64 + sl * 8];
            }
            #pragma unroll
            for (int ni = 0; ni < 4; ++ni) {
                int row = wc * 64 + ni * 16 + (l & 15);
                int sl = (eks * 4 + (l >> 4)) ^ (row & 7);
                bfv[ni] = *(const bf16x8*)&Bs[row * 64 + sl * 8];
            }
            __builtin_amdgcn_s_setprio(1);
            #pragma unroll
            for (int mi = 0; mi < 4; ++mi)
                #pragma unroll
                for (int ni = 0; ni < 4; ++ni)
                    acc[mi][ni] = __builtin_amdgcn_mfma_f32_16x16x32_bf16(
                        af[mi], bfv[ni], acc[mi][ni], 0, 0, 0);
            __builtin_amdgcn_s_setprio(0);
        }
        __syncthreads();
    }

    #pragma unroll
    for (int mi = 0; mi < 4; ++mi)
        #pragma unroll
        for (int ni = 0; ni < 4; ++ni) {
            int col = col0 + wc * 64 + ni * 16 + (l & 15);
            float bv = bias[col];
            int rowb = row0 + wr * 64 + mi * 16 + (l >> 4) * 4;
            if (omode == 2) {
                union { bf16_t h[4]; uint64_t q; } pk;
                #pragma unroll
                for (int j = 0; j < 4; ++j)
                    pk.h[j] = (bf16_t)(acc[mi][ni][j] + bv);
                *(uint64_t*)((bf16_t*)Cv + (size_t)col * M + rowb) = pk.q;
            } else if (omode == 1) {
                #pragma unroll
                for (int j = 0; j < 4; ++j)
                    ((float*)Cv)[(size_t)(rowb + j) * N + col] = acc[mi][ni][j] + bv;
            } else {
                #pragma unroll
                for (int j = 0; j < 4; ++j)
                    ((bf16_t*)Cv)[(size_t)(rowb + j) * N + col] = (bf16_t)(acc[mi][ni][j] + bv);
            }
        }
}

// ---------------------------------------------------------------------------
// Flash attention v8 = v7 with lsum moved to the MFMA pipe:
// lacc = mfma32(ones, P^T, lacc) per ks -> D[r][q] = sum_k P^T[k][q], same
// for all r and both lane-halves (C/D col = lane&31 = ql).  After the loop
// lacc[0] = full lsum(ql): kills the 32-long serial add chain, the per-tile
// shfl_xor, and rs-init.  A=ones is layout-immune.  Also: LDS read offsets
// hoisted (loop-invariant), gload source pointers strength-reduced.
// ---------------------------------------------------------------------------
__global__ __launch_bounds__(256)
void attn8_kernel(const bf16_t* __restrict__ qp, const bf16_t* __restrict__ kp,
                  const bf16_t* __restrict__ vT, bf16_t* __restrict__ o)
{
    __shared__ bf16_t Ks[2][4096];
    __shared__ bf16_t Vs[2][4096];
    const int bid = blockIdx.x;
    const int xcd = bid & 7, j = bid >> 3;
    const int bh = (xcd << 2) | (j & 3);
    const int qb = j >> 2;
    const int b = bh >> 4, h = bh & 15;
    const int t = threadIdx.x, w = t >> 6, l = t & 63;
    const int ql = l & 31, hh = l >> 5;
    const float M0 = 8.0f * 1.44269504f;

    const bf16_t* kbase = kp + ((size_t)b * 2048) * 1024 + h * 64;
    const bf16_t* vbase = vT + ((size_t)h * 64) * 4096 + (size_t)b * 2048;
    const int q0 = qb * 128 + w * 32;

    bf16x8 qf[4];
    {
        const bf16_t* qrow = qp + ((size_t)b * 2048 + q0 + ql) * 1024 + h * 64;
        const float qs = 0.125f * 1.44269504f;
        #pragma unroll
        for (int eks = 0; eks < 4; ++eks) {
            bf16x8 v = *(const bf16x8*)(qrow + eks * 16 + hh * 8);
            #pragma unroll
            for (int jj = 0; jj < 8; ++jj) v[jj] = (bf16_t)((float)v[jj] * qs);
            qf[eks] = v;
        }
    }

    // all-ones A-frag for the lsum MFMA (bf16 1.0 = 0x3F80)
    bf16x8 onesv;
    #pragma unroll
    for (int jj = 0; jj < 8; ++jj) onesv[jj] = (bf16_t)1.0f;

    f32x16 acc0, acc1, lacc;
    #pragma unroll
    for (int r = 0; r < 16; ++r) { acc0[r] = 0.f; acc1[r] = 0.f; lacc[r] = 0.f; }

    // hoisted loop-invariant LDS read offsets (same for Ks and Vs)
    int off_lo[4], off_hi[4];
    #pragma unroll
    for (int x = 0; x < 4; ++x) {
        off_lo[x] = ql * 64 + (((2 * x + hh) ^ (ql & 7)) * 8);
        off_hi[x] = (32 + ql) * 64 + (((2 * x + hh) ^ (ql & 7)) * 8);
    }

    const int ci0 = (w * 2) * 64 + l, ci1 = (w * 2 + 1) * 64 + l;
    const int gr0 = ci0 >> 3, gc0 = ci0 & 7, so0 = ((gc0 ^ (gr0 & 7)) * 8);
    const int gr1 = ci1 >> 3, gc1 = ci1 & 7, so1 = ((gc1 ^ (gr1 & 7)) * 8);

    // strength-reduced source pointers (advance per tile)
    const bf16_t* kq0 = kbase + (size_t)gr0 * 1024 + so0;
    const bf16_t* kq1 = kbase + (size_t)gr1 * 1024 + so1;
    const bf16_t* vq0 = vbase + (size_t)gr0 * 4096 + so0;
    const bf16_t* vq1 = vbase + (size_t)gr1 * 4096 + so1;

    GLOAD16(kq0, &Ks[0][(w * 2) * 512]);
    GLOAD16(kq1, &Ks[0][(w * 2 + 1) * 512]);
    GLOAD16(vq0, &Vs[0][(w * 2) * 512]);
    GLOAD16(vq1, &Vs[0][(w * 2 + 1) * 512]);
    __syncthreads();

    int cur = 0;
    for (int tile = 0; tile < 32; ++tile) {
        if (tile + 1 < 32) {                 // async prefetch next tile
            kq0 += 64 * 1024; kq1 += 64 * 1024;
            vq0 += 64;        vq1 += 64;
            GLOAD16(kq0, &Ks[cur ^ 1][(w * 2) * 512]);
            GLOAD16(kq1, &Ks[cur ^ 1][(w * 2 + 1) * 512]);
            GLOAD16(vq0, &Vs[cur ^ 1][(w * 2) * 512]);
            GLOAD16(vq1, &Vs[cur ^ 1][(w * 2 + 1) * 512]);
        }

        // ---- S^T = K Q^T, C-init = -M0 ----
        f32x16 sA, sB;
        #pragma unroll
        for (int r = 0; r < 16; ++r) { sA[r] = -M0; sB[r] = -M0; }
        __builtin_amdgcn_s_setprio(1);
        #pragma unroll
        for (int eks = 0; eks < 4; ++eks) {
            bf16x8 k0 = *(const bf16x8*)&Ks[cur][off_lo[eks]];
            bf16x8 k1 = *(const bf16x8*)&Ks[cur][off_hi[eks]];
            sA = __builtin_amdgcn_mfma_f32_32x32x16_bf16(k0, qf[eks], sA, 0, 0, 0);
            sB = __builtin_amdgcn_mfma_f32_32x32x16_bf16(k1, qf[eks], sB, 0, 0, 0);
        }
        __builtin_amdgcn_s_setprio(0);

        // ---- P = exp2(S'), pack to bf16 (no rs accumulation) ----
        uint32_t wA[8], wB[8];
        #pragma unroll
        for (int i = 0; i < 8; ++i) {
            wA[i] = pack2(EXP2F(sA[2 * i]), EXP2F(sA[2 * i + 1]));
            wB[i] = pack2(EXP2F(sB[2 * i]), EXP2F(sB[2 * i + 1]));
        }

        // ---- O^T += V^T P^T ; lsum += ones^T P^T (MFMA pipe) ----
        #pragma unroll
        for (int ks = 0; ks < 4; ++ks) {
            const int base = (ks & 1) * 4;
            uint32_t a0 = (ks < 2) ? wA[base]     : wB[base];
            uint32_t a1 = (ks < 2) ? wA[base + 1] : wB[base + 1];
            uint32_t a2 = (ks < 2) ? wA[base + 2] : wB[base + 2];
            uint32_t a3 = (ks < 2) ? wA[base + 3] : wB[base + 3];
            asm volatile("v_permlane32_swap_b32 %0, %1" : "+v"(a0), "+v"(a2));
            asm volatile("v_permlane32_swap_b32 %0, %1" : "+v"(a1), "+v"(a3));
            union { uint32_t u[4]; bf16x8 v; } pb;
            pb.u[0] = a0; pb.u[1] = a1; pb.u[2] = a2; pb.u[3] = a3;
            bf16x8 v0 = *(const bf16x8*)&Vs[cur][off_lo[ks]];
            bf16x8 v1 = *(const bf16x8*)&Vs[cur][off_hi[ks]];
            __builtin_amdgcn_s_setprio(1);
            acc0 = __builtin_amdgcn_mfma_f32_32x32x16_bf16(v0, pb.v, acc0, 0, 0, 0);
            acc1 = __builtin_amdgcn_mfma_f32_32x32x16_bf16(v1, pb.v, acc1, 0, 0, 0);
            lacc = __builtin_amdgcn_mfma_f32_32x32x16_bf16(onesv, pb.v, lacc, 0, 0, 0);
            __builtin_amdgcn_s_setprio(0);
        }

        __syncthreads();
        cur ^= 1;
    }

    // ---- epilogue: normalize by lacc[0] (= lsum for col ql, both halves) ----
    bf16_t* sc = &Ks[0][0];
    const float inv = 1.0f / lacc[0];
    #pragma unroll
    for (int r = 0; r < 16; ++r) {
        int e = (r & 3) + 8 * (r >> 2) + 4 * hh;
        sc[w * 2048 + ql * 64 + (((e >> 3) ^ (ql & 7)) * 8) + (e & 7)] =
            (bf16_t)(acc0[r] * inv);
        int e2 = e + 32;
        sc[w * 2048 + ql * 64 + (((e2 >> 3) ^ (ql & 7)) * 8) + (e2 & 7)] =
            (bf16_t)(acc1[r] * inv);
    }
    __syncthreads();
    #pragma unroll
    for (int it = 0; it < 4; ++it) {
        int ci = it * 64 + l;
        int qr = ci >> 3, ec = ci & 7;
        bf16x8 ov = *(const bf16x8*)&sc[w * 2048 + qr * 64 + ((ec ^ (qr & 7)) * 8)];
        *(bf16x8*)(o + ((size_t)b * 2048 + q0 + qr) * 1024 + h * 64 + ec * 8) = ov;
    }
}

// ---------------------------------------------------------------------------
extern "C" void kernel_launch(void* const* d_in, const int* in_sizes, int n_in,
                              void* d_out, int out_size, void* d_ws, size_t ws_size,
                              hipStream_t stream)
{
    const float* Q  = (const float*)d_in[0];
    const float* K  = (const float*)d_in[1];
    const float* V  = (const float*)d_in[2];
    const float* Wq = (const float*)d_in[3];
    const float* bq = (const float*)d_in[4];
    const float* Wk = (const float*)d_in[5];
    const float* bk = (const float*)d_in[6];
    const float* Wv = (const float*)d_in[7];
    const float* bv = (const float*)d_in[8];
    const float* We = (const float*)d_in[9];
    const float* be = (const float*)d_in[10];
    float* out = (float*)d_out;

    bf16_t* ws = (bf16_t*)d_ws;
    bf16_t* WqT = ws;                       // 1M elems each
    bf16_t* WkT = WqT + 1024 * 1024;
    bf16_t* WvT = WkT + 1024 * 1024;
    bf16_t* WeT = WvT + 1024 * 1024;
    bf16_t* qp  = WeT + 1024 * 1024;        // [4096][1024]
    bf16_t* kp  = qp  + 4096 * 1024;        // [4096][1024]
    bf16_t* vt  = kp  + 4096 * 1024;        // [1024][4096] (V proj transposed)
    bf16_t* ao  = vt  + 4096 * 1024;        // [4096][1024]
    bf16_t* Qb  = ao  + 4096 * 1024;        // bf16 input copies
    bf16_t* Kb  = Qb  + 4096 * 1024;
    bf16_t* Vb  = Kb  + 4096 * 1024;        // 64 MB total (proven footprint)

    dim3 blk(256);

    hipLaunchKernelGGL(wtrans_kernel, dim3(16, 16, 4), blk, 0, stream,
                       Wq, Wk, Wv, We, WqT, WkT, WvT, WeT);

    hipLaunchKernelGGL(cvt_kernel, dim3(2048, 3), blk, 0, stream,
                       Q, K, V, Qb, Kb, Vb);

    hipLaunchKernelGGL((gemm3_kernel<true>), dim3(256, 3), blk, 0, stream,
                       Qb, Kb, Vb, WqT, WkT, WvT, bq, bk, bv,
                       (void*)qp, (void*)kp, (void*)vt);

    hipLaunchKernelGGL(attn8_kernel, dim3(512), blk, 0, stream,
                       qp, kp, vt, ao);

    hipLaunchKernelGGL((gemm3_kernel<false>), dim3(256, 1), blk, 0, stream,
                       ao, (const bf16_t*)nullptr, (const bf16_t*)nullptr,
                       WeT, (const bf16_t*)nullptr, (const bf16_t*)nullptr,
                       be, (const float*)nullptr, (const float*)nullptr,
                       (void*)out, (void*)nullptr, (void*)nullptr);
}